// Round 1
// baseline (714.345 us; speedup 1.0000x reference)
//
#include <hip/hip_runtime.h>

#define HDIM 256
#define NREL 16
#define NBLK 128

// ---------------- zero ----------------
__global__ void zero_kernel(float4* __restrict__ p, int n4) {
    for (int i = blockIdx.x * blockDim.x + threadIdx.x; i < n4; i += gridDim.x * blockDim.x)
        p[i] = make_float4(0.f, 0.f, 0.f, 0.f);
}

// ---------------- per-edge message + scatter-add ----------------
// msg[e, b, io] = sum_i x[src[e], b*2+i] * w[etype[e], b, i, io];  agg[dst[e]] += msg * norm[e]
__global__ __launch_bounds__(256) void edge_kernel(
    const float* __restrict__ xin,
    const int* __restrict__ src,
    const int* __restrict__ dst,
    const int* __restrict__ et,
    const float* __restrict__ norm,
    const float* __restrict__ w,   // (R, B, 2, 2) row-major
    float* __restrict__ agg,
    int E)
{
    // LDS copy transposed to [r][i][io][b] so per-edge reads are 2-way (free) not 8-way conflicts
    __shared__ float wt[NREL * 512];
    for (int j = threadIdx.x; j < NREL * 512; j += blockDim.x) {
        int io = j & 1, i = (j >> 1) & 1, b = (j >> 2) & (NBLK - 1), r = j >> 9;
        wt[((r * 2 + i) * 2 + io) * NBLK + b] = w[j];
    }
    __syncthreads();

    const int o = threadIdx.x;          // feature channel 0..255
    const int b = o >> 1, io = o & 1;

    for (int e = blockIdx.x; e < E; e += gridDim.x) {
        const int s = src[e], d = dst[e], r = et[e];
        const float nm = norm[e];
        const float xv = xin[s * HDIM + o];
        const float xp = __shfl_xor(xv, 1);
        const float x0 = io ? xp : xv;   // xs[b,0]
        const float x1 = io ? xv : xp;   // xs[b,1]
        const float* wr = &wt[r * 512 + io * NBLK + b];
        const float m = fmaf(x0, wr[0], x1 * wr[256]);
        atomicAdd(&agg[d * HDIM + o], m * nm);
    }
}

// ---------------- fused self-loop GEMM: out = [relu](A @ W + bias + agg) ----------------
// A: M x 256, W: 256 x 256 row-major. BM=BN=64, BK=16, 256 threads, 4x4 micro-tile.
template <int RELU>
__global__ __launch_bounds__(256) void fused_gemm(
    const float* __restrict__ A,
    const float* __restrict__ W,
    const float* __restrict__ bias,
    const float* __restrict__ agg,
    float* __restrict__ out,
    int M)
{
    __shared__ float As[16][68];   // [k][m], padded (68%32==4 -> 2-way max)
    __shared__ float Bs[16][68];   // [k][n]

    const int m0 = blockIdx.x * 64;
    const int n0 = blockIdx.y * 64;
    const int t  = threadIdx.x;
    const int tx = t & 15;         // col group
    const int ty = t >> 4;         // row group

    float acc[4][4] = {};

    for (int k0 = 0; k0 < HDIM; k0 += 16) {
        // A tile: rows m0..+63, cols k0..+15 -> As[k][m]
        {
            const int col  = t & 15;
            const int row0 = t >> 4;
            #pragma unroll
            for (int q = 0; q < 4; ++q) {
                const int row = row0 + q * 16;
                const int gm  = m0 + row;
                As[col][row] = (gm < M) ? A[gm * HDIM + k0 + col] : 0.f;
            }
        }
        // B tile: rows k0..+15, cols n0..+63 -> Bs[k][n]
        {
            const int bcol  = t & 63;
            const int brow0 = t >> 6;  // 0..3
            #pragma unroll
            for (int q = 0; q < 4; ++q) {
                const int brow = brow0 + q * 4;
                Bs[brow][bcol] = W[(k0 + brow) * HDIM + n0 + bcol];
            }
        }
        __syncthreads();

        #pragma unroll
        for (int k = 0; k < 16; ++k) {
            float a[4], bv[4];
            #pragma unroll
            for (int i = 0; i < 4; ++i) a[i] = As[k][ty * 4 + i];
            #pragma unroll
            for (int j = 0; j < 4; ++j) bv[j] = Bs[k][tx * 4 + j];
            #pragma unroll
            for (int i = 0; i < 4; ++i)
                #pragma unroll
                for (int j = 0; j < 4; ++j)
                    acc[i][j] = fmaf(a[i], bv[j], acc[i][j]);
        }
        __syncthreads();
    }

    #pragma unroll
    for (int i = 0; i < 4; ++i) {
        const int gm = m0 + ty * 4 + i;
        if (gm >= M) continue;
        #pragma unroll
        for (int j = 0; j < 4; ++j) {
            const int gn = n0 + tx * 4 + j;
            float v = acc[i][j] + bias[gn] + agg[gm * HDIM + gn];
            if (RELU) v = fmaxf(v, 0.f);
            out[gm * HDIM + gn] = v;
        }
    }
}

extern "C" void kernel_launch(void* const* d_in, const int* in_sizes, int n_in,
                              void* d_out, int out_size, void* d_ws, size_t ws_size,
                              hipStream_t stream) {
    const float* x    = (const float*)d_in[0];
    const int*   src  = (const int*)d_in[1];
    const int*   dst  = (const int*)d_in[2];
    const int*   et   = (const int*)d_in[3];
    const float* norm = (const float*)d_in[4];
    const float* w1   = (const float*)d_in[5];
    const float* lw1  = (const float*)d_in[6];
    const float* b1   = (const float*)d_in[7];
    const float* w2   = (const float*)d_in[8];
    const float* lw2  = (const float*)d_in[9];
    const float* b2   = (const float*)d_in[10];

    const int M = in_sizes[0] / HDIM;
    const int E = in_sizes[1];

    float* out = (float*)d_out;
    float* h   = (float*)d_ws;          // M*HDIM floats = 20.5 MB scratch

    const int n4 = (M * HDIM) / 4;
    dim3 gg((M + 63) / 64, HDIM / 64);

    // Layer 1: agg1 -> d_out (as scratch accumulator), h = relu(agg1 + b1 + x@lw1)
    zero_kernel<<<2048, 256, 0, stream>>>((float4*)out, n4);
    edge_kernel<<<4096, 256, 0, stream>>>(x, src, dst, et, norm, w1, out, E);
    fused_gemm<1><<<gg, 256, 0, stream>>>(x, lw1, b1, out, h, M);

    // Layer 2: agg2 -> d_out, final out = agg2 + b2 + h@lw2 (in-place epilogue)
    zero_kernel<<<2048, 256, 0, stream>>>((float4*)out, n4);
    edge_kernel<<<4096, 256, 0, stream>>>(h, src, dst, et, norm, w2, out, E);
    fused_gemm<0><<<gg, 256, 0, stream>>>(h, lw2, b2, out, out, M);
}

// Round 2
// 468.728 us; speedup vs baseline: 1.5240x; 1.5240x over previous
//
#include <hip/hip_runtime.h>

#define HDIM 256
#define NREL 16
#define NBLK 128

// ---------------- zero (fallback path only) ----------------
__global__ void zero_kernel(float4* __restrict__ p, int n4) {
    for (int i = blockIdx.x * blockDim.x + threadIdx.x; i < n4; i += gridDim.x * blockDim.x)
        p[i] = make_float4(0.f, 0.f, 0.f, 0.f);
}

// ---------------- counting-sort by dst: histogram ----------------
__global__ void hist_kernel(const int* __restrict__ dst, int* __restrict__ deg, int E) {
    for (int e = blockIdx.x * blockDim.x + threadIdx.x; e < E; e += gridDim.x * blockDim.x)
        atomicAdd(&deg[dst[e]], 1);
}

// ---------------- single-block exclusive scan over N bins ----------------
__global__ __launch_bounds__(1024) void scan_kernel(const int* __restrict__ deg,
                                                    int* __restrict__ start,
                                                    int* __restrict__ cnt, int N) {
    __shared__ int part[1024];
    const int t = threadIdx.x;
    const int CH = (N + 1023) >> 10;
    const int c0 = t * CH;
    int sum = 0;
    for (int i = 0; i < CH; ++i) { int idx = c0 + i; if (idx < N) sum += deg[idx]; }
    part[t] = sum;
    __syncthreads();
    for (int off = 1; off < 1024; off <<= 1) {
        int v = (t >= off) ? part[t - off] : 0;
        __syncthreads();
        part[t] += v;
        __syncthreads();
    }
    int run = (t > 0) ? part[t - 1] : 0;
    for (int i = 0; i < CH; ++i) {
        int idx = c0 + i;
        if (idx < N) { start[idx] = run; cnt[idx] = run; run += deg[idx]; }
    }
    if (t == 1023) start[N] = part[1023];
}

// ---------------- scatter edges into dst-sorted order (packed payload) ----------------
__global__ void scatter_kernel(const int* __restrict__ src, const int* __restrict__ dst,
                               const int* __restrict__ et, const float* __restrict__ norm,
                               int* __restrict__ cnt, int2* __restrict__ epack, int E) {
    for (int e = blockIdx.x * blockDim.x + threadIdx.x; e < E; e += gridDim.x * blockDim.x) {
        int d = dst[e];
        int pos = atomicAdd(&cnt[d], 1);
        epack[pos] = make_int2(src[e] * NREL + et[e], __float_as_int(norm[e]));
    }
}

// ---------------- pull-mode aggregation: no atomics ----------------
// agg[d, o] = sum over edges e with dst==d of norm_e * (x0*w[r,b,0,io] + x1*w[r,b,1,io])
__global__ __launch_bounds__(256) void agg_kernel(
    const float* __restrict__ xin,
    const int2* __restrict__ epack,
    const int* __restrict__ start,
    const float* __restrict__ w,   // (R, B, 2, 2) row-major
    float* __restrict__ agg,
    int N)
{
    // LDS copy transposed to [r][i][io][b]: per-edge wave read = 2 lanes/bank (free)
    __shared__ float wt[NREL * 512];
    for (int j = threadIdx.x; j < NREL * 512; j += blockDim.x) {
        int io = j & 1, i = (j >> 1) & 1, b = (j >> 2) & (NBLK - 1), r = j >> 9;
        wt[((r * 2 + i) * 2 + io) * NBLK + b] = w[j];
    }
    __syncthreads();

    const int o = threadIdx.x;           // channel
    const int b = o >> 1, io = o & 1;
    const float* wbase = &wt[io * NBLK + b];

    for (int d = blockIdx.x; d < N; d += gridDim.x) {
        const int s0 = start[d], s1 = start[d + 1];
        float acc = 0.f;
        for (int idx = s0; idx < s1; ++idx) {
            const int2 ep = epack[idx];            // uniform per block -> scalar load
            const int   s  = ep.x >> 4;
            const int   r  = ep.x & (NREL - 1);
            const float nm = __int_as_float(ep.y);
            const float2 xv = *(const float2*)(xin + s * HDIM + (b << 1));
            const float* wr = wbase + r * 512;
            acc = fmaf(nm, fmaf(xv.x, wr[0], xv.y * wr[256]), acc);
        }
        agg[d * HDIM + o] = acc;
    }
}

// ---------------- fallback: per-edge atomic scatter (if ws too small) ----------------
__global__ __launch_bounds__(256) void edge_kernel(
    const float* __restrict__ xin,
    const int* __restrict__ src,
    const int* __restrict__ dst,
    const int* __restrict__ et,
    const float* __restrict__ norm,
    const float* __restrict__ w,
    float* __restrict__ agg,
    int E)
{
    __shared__ float wt[NREL * 512];
    for (int j = threadIdx.x; j < NREL * 512; j += blockDim.x) {
        int io = j & 1, i = (j >> 1) & 1, b = (j >> 2) & (NBLK - 1), r = j >> 9;
        wt[((r * 2 + i) * 2 + io) * NBLK + b] = w[j];
    }
    __syncthreads();
    const int o = threadIdx.x;
    const int b = o >> 1, io = o & 1;
    for (int e = blockIdx.x; e < E; e += gridDim.x) {
        const int s = src[e], d = dst[e], r = et[e];
        const float nm = norm[e];
        const float2 xv = *(const float2*)(xin + s * HDIM + (b << 1));
        const float* wr = &wt[r * 512 + io * NBLK + b];
        const float m = fmaf(xv.x, wr[0], xv.y * wr[256]);
        atomicAdd(&agg[d * HDIM + o], m * nm);
    }
}

// ---------------- fused self-loop GEMM: out = [relu](A @ W + bias + agg) ----------------
template <int RELU>
__global__ __launch_bounds__(256) void fused_gemm(
    const float* __restrict__ A,
    const float* __restrict__ W,
    const float* __restrict__ bias,
    const float* __restrict__ agg,
    float* __restrict__ out,
    int M)
{
    __shared__ float As[16][68];
    __shared__ float Bs[16][68];

    const int m0 = blockIdx.x * 64;
    const int n0 = blockIdx.y * 64;
    const int t  = threadIdx.x;
    const int tx = t & 15;
    const int ty = t >> 4;

    float acc[4][4] = {};

    for (int k0 = 0; k0 < HDIM; k0 += 16) {
        {
            const int col  = t & 15;
            const int row0 = t >> 4;
            #pragma unroll
            for (int q = 0; q < 4; ++q) {
                const int row = row0 + q * 16;
                const int gm  = m0 + row;
                As[col][row] = (gm < M) ? A[gm * HDIM + k0 + col] : 0.f;
            }
        }
        {
            const int bcol  = t & 63;
            const int brow0 = t >> 6;
            #pragma unroll
            for (int q = 0; q < 4; ++q) {
                const int brow = brow0 + q * 4;
                Bs[brow][bcol] = W[(k0 + brow) * HDIM + n0 + bcol];
            }
        }
        __syncthreads();

        #pragma unroll
        for (int k = 0; k < 16; ++k) {
            float a[4], bv[4];
            #pragma unroll
            for (int i = 0; i < 4; ++i) a[i] = As[k][ty * 4 + i];
            #pragma unroll
            for (int j = 0; j < 4; ++j) bv[j] = Bs[k][tx * 4 + j];
            #pragma unroll
            for (int i = 0; i < 4; ++i)
                #pragma unroll
                for (int j = 0; j < 4; ++j)
                    acc[i][j] = fmaf(a[i], bv[j], acc[i][j]);
        }
        __syncthreads();
    }

    #pragma unroll
    for (int i = 0; i < 4; ++i) {
        const int gm = m0 + ty * 4 + i;
        if (gm >= M) continue;
        #pragma unroll
        for (int j = 0; j < 4; ++j) {
            const int gn = n0 + tx * 4 + j;
            float v = acc[i][j] + bias[gn] + agg[gm * HDIM + gn];
            if (RELU) v = fmaxf(v, 0.f);
            out[gm * HDIM + gn] = v;
        }
    }
}

extern "C" void kernel_launch(void* const* d_in, const int* in_sizes, int n_in,
                              void* d_out, int out_size, void* d_ws, size_t ws_size,
                              hipStream_t stream) {
    const float* x    = (const float*)d_in[0];
    const int*   src  = (const int*)d_in[1];
    const int*   dst  = (const int*)d_in[2];
    const int*   et   = (const int*)d_in[3];
    const float* norm = (const float*)d_in[4];
    const float* w1   = (const float*)d_in[5];
    const float* lw1  = (const float*)d_in[6];
    const float* b1   = (const float*)d_in[7];
    const float* w2   = (const float*)d_in[8];
    const float* lw2  = (const float*)d_in[9];
    const float* b2   = (const float*)d_in[10];

    const int M = in_sizes[0] / HDIM;   // 20000 nodes
    const int E = in_sizes[1];          // 320000 edges

    float* out = (float*)d_out;
    char*  ws  = (char*)d_ws;

    // ws layout
    size_t off = 0;
    float* h = (float*)(ws + off);              off += (size_t)M * HDIM * 4;
    int* start = (int*)(ws + off);              off += (size_t)(M + 1) * 4;  off = (off + 15) & ~15ull;
    int* cnt   = (int*)(ws + off);              off += (size_t)M * 4;        off = (off + 15) & ~15ull;
    int* deg   = (int*)(ws + off);              off += (size_t)M * 4;        off = (off + 15) & ~15ull;
    int2* epack = (int2*)(ws + off);            off += (size_t)E * 8;

    dim3 gg((M + 63) / 64, HDIM / 64);
    const int n4 = (M * HDIM) / 4;

    if (off <= ws_size) {
        // ---- sorted, atomic-free path ----
        hipMemsetAsync(deg, 0, (size_t)M * 4, stream);
        hist_kernel<<<512, 256, 0, stream>>>(dst, deg, E);
        scan_kernel<<<1, 1024, 0, stream>>>(deg, start, cnt, M);
        scatter_kernel<<<512, 256, 0, stream>>>(src, dst, et, norm, cnt, epack, E);

        // Layer 1: agg1 -> d_out (scratch), h = relu(agg1 + b1 + x@lw1)
        agg_kernel<<<2560, 256, 0, stream>>>(x, epack, start, w1, out, M);
        fused_gemm<1><<<gg, 256, 0, stream>>>(x, lw1, b1, out, h, M);

        // Layer 2: agg2 -> d_out, final = agg2 + b2 + h@lw2 (in-place epilogue)
        agg_kernel<<<2560, 256, 0, stream>>>(h, epack, start, w2, out, M);
        fused_gemm<0><<<gg, 256, 0, stream>>>(h, lw2, b2, out, out, M);
    } else {
        // ---- fallback: atomic scatter path ----
        zero_kernel<<<2048, 256, 0, stream>>>((float4*)out, n4);
        edge_kernel<<<4096, 256, 0, stream>>>(x, src, dst, et, norm, w1, out, E);
        fused_gemm<1><<<gg, 256, 0, stream>>>(x, lw1, b1, out, h, M);

        zero_kernel<<<2048, 256, 0, stream>>>((float4*)out, n4);
        edge_kernel<<<4096, 256, 0, stream>>>(h, src, dst, et, norm, w2, out, E);
        fused_gemm<0><<<gg, 256, 0, stream>>>(h, lw2, b2, out, out, M);
    }
}

// Round 3
// 277.040 us; speedup vs baseline: 2.5785x; 1.6919x over previous
//
#include <hip/hip_runtime.h>

#define HDIM 256
#define NREL 16
#define NBLK 128

// ---------------- counting-sort by dst: histogram ----------------
__global__ void hist_kernel(const int* __restrict__ dst, int* __restrict__ deg, int E) {
    for (int e = blockIdx.x * blockDim.x + threadIdx.x; e < E; e += gridDim.x * blockDim.x)
        atomicAdd(&deg[dst[e]], 1);
}

// ---------------- single-block exclusive scan over N bins ----------------
__global__ __launch_bounds__(1024) void scan_kernel(const int* __restrict__ deg,
                                                    int* __restrict__ start,
                                                    int* __restrict__ cnt, int N) {
    __shared__ int part[1024];
    const int t = threadIdx.x;
    const int CH = (N + 1023) >> 10;
    const int c0 = t * CH;
    int sum = 0;
    for (int i = 0; i < CH; ++i) { int idx = c0 + i; if (idx < N) sum += deg[idx]; }
    part[t] = sum;
    __syncthreads();
    for (int off = 1; off < 1024; off <<= 1) {
        int v = (t >= off) ? part[t - off] : 0;
        __syncthreads();
        part[t] += v;
        __syncthreads();
    }
    int run = (t > 0) ? part[t - 1] : 0;
    for (int i = 0; i < CH; ++i) {
        int idx = c0 + i;
        if (idx < N) { start[idx] = run; cnt[idx] = run; run += deg[idx]; }
    }
    if (t == 1023) start[N] = part[1023];
}

// ---------------- scatter edges into dst-sorted order (packed payload) ----------------
__global__ void scatter_kernel(const int* __restrict__ src, const int* __restrict__ dst,
                               const int* __restrict__ et, const float* __restrict__ norm,
                               int* __restrict__ cnt, int2* __restrict__ epack, int E) {
    for (int e = blockIdx.x * blockDim.x + threadIdx.x; e < E; e += gridDim.x * blockDim.x) {
        int d = dst[e];
        int pos = atomicAdd(&cnt[d], 1);
        epack[pos] = make_int2(src[e] * NREL + et[e], __float_as_int(norm[e]));
    }
}

// ---------------- per-edge micro-matmul for one lane (blocks 2l, 2l+1) ----------------
__device__ __forceinline__ float4 edge_step(float4 acc, float4 xv, int2 e, const float* wl) {
    const int   r  = e.x & (NREL - 1);
    const float nm = __int_as_float(e.y);
    const float* p = wl + r * 512;
    const float2 w00 = *(const float2*)(p);         // i=0, io=0 : blocks 2l, 2l+1
    const float2 w01 = *(const float2*)(p + 128);   // i=0, io=1
    const float2 w10 = *(const float2*)(p + 256);   // i=1, io=0
    const float2 w11 = *(const float2*)(p + 384);   // i=1, io=1
    acc.x = fmaf(nm, fmaf(xv.x, w00.x, xv.y * w10.x), acc.x);
    acc.y = fmaf(nm, fmaf(xv.x, w01.x, xv.y * w11.x), acc.y);
    acc.z = fmaf(nm, fmaf(xv.z, w00.y, xv.w * w10.y), acc.z);
    acc.w = fmaf(nm, fmaf(xv.z, w01.y, xv.w * w11.y), acc.w);
    return acc;
}

// ---------------- pull-mode aggregation: wave-per-node, unroll-4 ----------------
#define WPB 8  // waves per block
__global__ __launch_bounds__(512) void agg_kernel(
    const float* __restrict__ xin,
    const int2* __restrict__ epack,
    const int* __restrict__ start,
    const float* __restrict__ w,   // (R, B, 2, 2) row-major
    float* __restrict__ agg,
    int N)
{
    // wt[r][i][io][b]: lane-fixed float2 read at b=2l covers both of the lane's blocks
    __shared__ float wt[NREL * 512];
    for (int j = threadIdx.x; j < NREL * 512; j += blockDim.x) {
        int io = j & 1, i = (j >> 1) & 1, b = (j >> 2) & (NBLK - 1), r = j >> 9;
        wt[((r * 2 + i) * 2 + io) * NBLK + b] = w[j];
    }
    __syncthreads();

    const int wv = threadIdx.x >> 6;   // wave in block
    const int l  = threadIdx.x & 63;   // lane: channels 4l..4l+3
    const float* wl = wt + 2 * l;
    const int c = 4 * l;

    for (int d = blockIdx.x * WPB + wv; d < N; d += gridDim.x * WPB) {
        const int s0 = start[d], s1 = start[d + 1];
        float4 acc = make_float4(0.f, 0.f, 0.f, 0.f);
        int idx = s0;
        for (; idx + 4 <= s1; idx += 4) {
            const int2 e0 = epack[idx + 0];
            const int2 e1 = epack[idx + 1];
            const int2 e2 = epack[idx + 2];
            const int2 e3 = epack[idx + 3];
            const float4 xa = *(const float4*)(xin + (e0.x >> 4) * HDIM + c);
            const float4 xb = *(const float4*)(xin + (e1.x >> 4) * HDIM + c);
            const float4 xc = *(const float4*)(xin + (e2.x >> 4) * HDIM + c);
            const float4 xd = *(const float4*)(xin + (e3.x >> 4) * HDIM + c);
            acc = edge_step(acc, xa, e0, wl);
            acc = edge_step(acc, xb, e1, wl);
            acc = edge_step(acc, xc, e2, wl);
            acc = edge_step(acc, xd, e3, wl);
        }
        for (; idx < s1; ++idx) {
            const int2 e0 = epack[idx];
            const float4 xa = *(const float4*)(xin + (e0.x >> 4) * HDIM + c);
            acc = edge_step(acc, xa, e0, wl);
        }
        *(float4*)(agg + d * HDIM + c) = acc;
    }
}

// ---------------- fused self-loop GEMM: out = [relu](A @ W + bias + agg) ----------------
template <int RELU>
__global__ __launch_bounds__(256) void fused_gemm(
    const float* __restrict__ A,
    const float* __restrict__ W,
    const float* __restrict__ bias,
    const float* __restrict__ agg,
    float* __restrict__ out,
    int M)
{
    __shared__ float As[16][68];
    __shared__ float Bs[16][68];

    const int m0 = blockIdx.x * 64;
    const int n0 = blockIdx.y * 64;
    const int t  = threadIdx.x;
    const int tx = t & 15;
    const int ty = t >> 4;

    float acc[4][4] = {};

    for (int k0 = 0; k0 < HDIM; k0 += 16) {
        {
            const int col  = t & 15;
            const int row0 = t >> 4;
            #pragma unroll
            for (int q = 0; q < 4; ++q) {
                const int row = row0 + q * 16;
                const int gm  = m0 + row;
                As[col][row] = (gm < M) ? A[gm * HDIM + k0 + col] : 0.f;
            }
        }
        {
            const int bcol  = t & 63;
            const int brow0 = t >> 6;
            #pragma unroll
            for (int q = 0; q < 4; ++q) {
                const int brow = brow0 + q * 4;
                Bs[brow][bcol] = W[(k0 + brow) * HDIM + n0 + bcol];
            }
        }
        __syncthreads();

        #pragma unroll
        for (int k = 0; k < 16; ++k) {
            float a[4], bv[4];
            #pragma unroll
            for (int i = 0; i < 4; ++i) a[i] = As[k][ty * 4 + i];
            #pragma unroll
            for (int j = 0; j < 4; ++j) bv[j] = Bs[k][tx * 4 + j];
            #pragma unroll
            for (int i = 0; i < 4; ++i)
                #pragma unroll
                for (int j = 0; j < 4; ++j)
                    acc[i][j] = fmaf(a[i], bv[j], acc[i][j]);
        }
        __syncthreads();
    }

    #pragma unroll
    for (int i = 0; i < 4; ++i) {
        const int gm = m0 + ty * 4 + i;
        if (gm >= M) continue;
        #pragma unroll
        for (int j = 0; j < 4; ++j) {
            const int gn = n0 + tx * 4 + j;
            float v = acc[i][j] + bias[gn] + agg[gm * HDIM + gn];
            if (RELU) v = fmaxf(v, 0.f);
            out[gm * HDIM + gn] = v;
        }
    }
}

extern "C" void kernel_launch(void* const* d_in, const int* in_sizes, int n_in,
                              void* d_out, int out_size, void* d_ws, size_t ws_size,
                              hipStream_t stream) {
    const float* x    = (const float*)d_in[0];
    const int*   src  = (const int*)d_in[1];
    const int*   dst  = (const int*)d_in[2];
    const int*   et   = (const int*)d_in[3];
    const float* norm = (const float*)d_in[4];
    const float* w1   = (const float*)d_in[5];
    const float* lw1  = (const float*)d_in[6];
    const float* b1   = (const float*)d_in[7];
    const float* w2   = (const float*)d_in[8];
    const float* lw2  = (const float*)d_in[9];
    const float* b2   = (const float*)d_in[10];

    const int M = in_sizes[0] / HDIM;   // 20000 nodes
    const int E = in_sizes[1];          // 320000 edges

    float* out = (float*)d_out;
    char*  ws  = (char*)d_ws;

    // ws layout
    size_t off = 0;
    float* h = (float*)(ws + off);              off += (size_t)M * HDIM * 4;
    int* start = (int*)(ws + off);              off += (size_t)(M + 1) * 4;  off = (off + 15) & ~15ull;
    int* cnt   = (int*)(ws + off);              off += (size_t)M * 4;        off = (off + 15) & ~15ull;
    int* deg   = (int*)(ws + off);              off += (size_t)M * 4;        off = (off + 15) & ~15ull;
    int2* epack = (int2*)(ws + off);            off += (size_t)E * 8;

    dim3 gg((M + 63) / 64, HDIM / 64);

    // ---- preprocessing: dst-sorted CSR (built every call; deterministic) ----
    hipMemsetAsync(deg, 0, (size_t)M * 4, stream);
    hist_kernel<<<512, 256, 0, stream>>>(dst, deg, E);
    scan_kernel<<<1, 1024, 0, stream>>>(deg, start, cnt, M);
    scatter_kernel<<<512, 256, 0, stream>>>(src, dst, et, norm, cnt, epack, E);

    const int nblk = (M + WPB - 1) / WPB;

    // Layer 1: agg1 -> d_out (scratch), h = relu(agg1 + b1 + x@lw1)
    agg_kernel<<<nblk, 512, 0, stream>>>(x, epack, start, w1, out, M);
    fused_gemm<1><<<gg, 256, 0, stream>>>(x, lw1, b1, out, h, M);

    // Layer 2: agg2 -> d_out, final = agg2 + b2 + h@lw2 (in-place epilogue)
    agg_kernel<<<nblk, 512, 0, stream>>>(h, epack, start, w2, out, M);
    fused_gemm<0><<<gg, 256, 0, stream>>>(h, lw2, b2, out, out, M);
}

// Round 4
// 219.196 us; speedup vs baseline: 3.2589x; 1.2639x over previous
//
#include <hip/hip_runtime.h>

#define HDIM 256
#define NREL 16
#define NBLK 128

typedef __attribute__((ext_vector_type(8))) short bf16x8;
typedef __attribute__((ext_vector_type(4))) float f32x4;

__device__ __forceinline__ unsigned short f2bf(float f) {
    unsigned int u = __float_as_uint(f);
    u = (u + 0x7FFFu + ((u >> 16) & 1u)) >> 16;   // RNE
    return (unsigned short)u;
}

// ---------------- counting-sort by dst: histogram ----------------
__global__ void hist_kernel(const int* __restrict__ dst, int* __restrict__ deg, int E) {
    for (int e = blockIdx.x * blockDim.x + threadIdx.x; e < E; e += gridDim.x * blockDim.x)
        atomicAdd(&deg[dst[e]], 1);
}

// ---------------- single-block exclusive scan over N bins ----------------
__global__ __launch_bounds__(1024) void scan_kernel(const int* __restrict__ deg,
                                                    int* __restrict__ start,
                                                    int* __restrict__ cnt, int N) {
    __shared__ int part[1024];
    const int t = threadIdx.x;
    const int CH = (N + 1023) >> 10;
    const int c0 = t * CH;
    int sum = 0;
    for (int i = 0; i < CH; ++i) { int idx = c0 + i; if (idx < N) sum += deg[idx]; }
    part[t] = sum;
    __syncthreads();
    for (int off = 1; off < 1024; off <<= 1) {
        int v = (t >= off) ? part[t - off] : 0;
        __syncthreads();
        part[t] += v;
        __syncthreads();
    }
    int run = (t > 0) ? part[t - 1] : 0;
    for (int i = 0; i < CH; ++i) {
        int idx = c0 + i;
        if (idx < N) { start[idx] = run; cnt[idx] = run; run += deg[idx]; }
    }
    if (t == 1023) start[N] = part[1023];
}

// ---------------- scatter edges into dst-sorted order (packed payload) ----------------
__global__ void scatter_kernel(const int* __restrict__ src, const int* __restrict__ dst,
                               const int* __restrict__ et, const float* __restrict__ norm,
                               int* __restrict__ cnt, int2* __restrict__ epack, int E) {
    for (int e = blockIdx.x * blockDim.x + threadIdx.x; e < E; e += gridDim.x * blockDim.x) {
        int d = dst[e];
        int pos = atomicAdd(&cnt[d], 1);
        epack[pos] = make_int2(src[e] * NREL + et[e], __float_as_int(norm[e]));
    }
}

// ---------------- converts: x -> bf16, loop_w -> bf16 transposed ----------------
__global__ void convert_kernel(const float* __restrict__ x, unsigned short* __restrict__ xb,
                               const float* __restrict__ lw1, unsigned short* __restrict__ w1t,
                               const float* __restrict__ lw2, unsigned short* __restrict__ w2t,
                               int nx) {
    const int total = nx + 2 * 65536;
    for (int i = blockIdx.x * blockDim.x + threadIdx.x; i < total; i += gridDim.x * blockDim.x) {
        if (i < nx) {
            xb[i] = f2bf(x[i]);
        } else if (i < nx + 65536) {
            int j = i - nx;
            int n = j >> 8, k = j & 255;
            w1t[j] = f2bf(lw1[k * HDIM + n]);   // W^T[n][k]
        } else {
            int j = i - nx - 65536;
            int n = j >> 8, k = j & 255;
            w2t[j] = f2bf(lw2[k * HDIM + n]);
        }
    }
}

// ---------------- per-edge micro-matmul for one lane (blocks 2l, 2l+1) ----------------
__device__ __forceinline__ float4 edge_step(float4 acc, ushort4 xq, int2 e, const float* wl) {
    const int   r  = e.x & (NREL - 1);
    const float nm = __int_as_float(e.y);
    const float* p = wl + r * 512;
    const float2 w00 = *(const float2*)(p);         // i=0, io=0
    const float2 w01 = *(const float2*)(p + 128);   // i=0, io=1
    const float2 w10 = *(const float2*)(p + 256);   // i=1, io=0
    const float2 w11 = *(const float2*)(p + 384);   // i=1, io=1
    const float x0 = __uint_as_float((unsigned int)xq.x << 16);
    const float x1 = __uint_as_float((unsigned int)xq.y << 16);
    const float x2 = __uint_as_float((unsigned int)xq.z << 16);
    const float x3 = __uint_as_float((unsigned int)xq.w << 16);
    acc.x = fmaf(nm, fmaf(x0, w00.x, x1 * w10.x), acc.x);
    acc.y = fmaf(nm, fmaf(x0, w01.x, x1 * w11.x), acc.y);
    acc.z = fmaf(nm, fmaf(x2, w00.y, x3 * w10.y), acc.z);
    acc.w = fmaf(nm, fmaf(x2, w01.y, x3 * w11.y), acc.w);
    return acc;
}

// ---------------- pull-mode aggregation: wave-per-node, bf16 gather, unroll-4 ----------------
#define WPB 8
__global__ __launch_bounds__(512) void agg_kernel(
    const unsigned short* __restrict__ xin,  // bf16 [N,256]
    const int2* __restrict__ epack,
    const int* __restrict__ start,
    const float* __restrict__ w,             // (R, B, 2, 2) f32
    float* __restrict__ agg,
    int N)
{
    __shared__ float wt[NREL * 512];   // [r][i][io][b]
    for (int j = threadIdx.x; j < NREL * 512; j += blockDim.x) {
        int io = j & 1, i = (j >> 1) & 1, b = (j >> 2) & (NBLK - 1), r = j >> 9;
        wt[((r * 2 + i) * 2 + io) * NBLK + b] = w[j];
    }
    __syncthreads();

    const int wv = threadIdx.x >> 6;
    const int l  = threadIdx.x & 63;   // lane: channels 4l..4l+3
    const float* wl = wt + 2 * l;
    const int c = 4 * l;

    for (int d = blockIdx.x * WPB + wv; d < N; d += gridDim.x * WPB) {
        const int s0 = start[d], s1 = start[d + 1];
        float4 acc = make_float4(0.f, 0.f, 0.f, 0.f);
        int idx = s0;
        for (; idx + 4 <= s1; idx += 4) {
            const int2 e0 = epack[idx + 0];
            const int2 e1 = epack[idx + 1];
            const int2 e2 = epack[idx + 2];
            const int2 e3 = epack[idx + 3];
            const ushort4 xa = *(const ushort4*)(xin + (size_t)(e0.x >> 4) * HDIM + c);
            const ushort4 xb = *(const ushort4*)(xin + (size_t)(e1.x >> 4) * HDIM + c);
            const ushort4 xc = *(const ushort4*)(xin + (size_t)(e2.x >> 4) * HDIM + c);
            const ushort4 xd = *(const ushort4*)(xin + (size_t)(e3.x >> 4) * HDIM + c);
            acc = edge_step(acc, xa, e0, wl);
            acc = edge_step(acc, xb, e1, wl);
            acc = edge_step(acc, xc, e2, wl);
            acc = edge_step(acc, xd, e3, wl);
        }
        for (; idx < s1; ++idx) {
            const int2 e0 = epack[idx];
            const ushort4 xa = *(const ushort4*)(xin + (size_t)(e0.x >> 4) * HDIM + c);
            acc = edge_step(acc, xa, e0, wl);
        }
        *(float4*)(agg + (size_t)d * HDIM + c) = acc;
    }
}

// ---------------- MFMA self-loop GEMM: bf16 A @ bf16 W^T + bias + agg ----------------
// Block = 256 thr = 4 waves; block covers 32 m-rows x 256 n-cols (wave wv: n0 = 64*wv).
// WRITE_BF=1: hb[gm][gn] = bf16(relu(v))  (hb may alias A; __syncthreads drains A reads first)
// WRITE_BF=0: outF[gm][gn] = v            (outF aliases agg element-wise per thread: safe)
template <int WRITE_BF>
__global__ __launch_bounds__(256) void mfma_gemm(
    const unsigned short* A,                  // [M,256] bf16 (no restrict: may alias hb)
    const unsigned short* __restrict__ BT,    // [256,256] bf16, BT[n][k] = W[k][n]
    const float* __restrict__ bias,
    const float* __restrict__ agg,
    float* __restrict__ outF,
    unsigned short* hb,
    int M)
{
    const int wv = threadIdx.x >> 6;
    const int l  = threadIdx.x & 63;
    const int lr = l & 15;          // A row / B col / D col group
    const int lk = l >> 4;          // k group
    const int mblk = blockIdx.x * 32;
    const int n0 = wv * 64;

    f32x4 acc[2][4] = {};

    const unsigned short* arow0 = A + (size_t)(mblk + lr) * HDIM + lk * 8;
    const unsigned short* arow1 = arow0 + 16 * HDIM;
    const unsigned short* brow0 = BT + (size_t)(n0 + lr) * HDIM + lk * 8;

    #pragma unroll
    for (int ks = 0; ks < 8; ++ks) {
        const int k0 = ks * 32;
        const bf16x8 a0 = *(const bf16x8*)(arow0 + k0);
        const bf16x8 a1 = *(const bf16x8*)(arow1 + k0);
        #pragma unroll
        for (int j = 0; j < 4; ++j) {
            const bf16x8 b = *(const bf16x8*)(brow0 + j * 16 * HDIM + k0);
            acc[0][j] = __builtin_amdgcn_mfma_f32_16x16x32_bf16(a0, b, acc[0][j], 0, 0, 0);
            acc[1][j] = __builtin_amdgcn_mfma_f32_16x16x32_bf16(a1, b, acc[1][j], 0, 0, 0);
        }
    }

    __syncthreads();   // drain all A global reads before (possibly aliased) hb writes

    #pragma unroll
    for (int i = 0; i < 2; ++i) {
        #pragma unroll
        for (int j = 0; j < 4; ++j) {
            const int gn = n0 + 16 * j + lr;
            const float bv = bias[gn];
            #pragma unroll
            for (int q = 0; q < 4; ++q) {
                const int gm = mblk + 16 * i + lk * 4 + q;
                if (gm < M) {
                    float v = acc[i][j][q] + bv + agg[(size_t)gm * HDIM + gn];
                    if (WRITE_BF) {
                        v = fmaxf(v, 0.f);
                        hb[(size_t)gm * HDIM + gn] = f2bf(v);
                    } else {
                        outF[(size_t)gm * HDIM + gn] = v;
                    }
                }
            }
        }
    }
}

extern "C" void kernel_launch(void* const* d_in, const int* in_sizes, int n_in,
                              void* d_out, int out_size, void* d_ws, size_t ws_size,
                              hipStream_t stream) {
    const float* x    = (const float*)d_in[0];
    const int*   src  = (const int*)d_in[1];
    const int*   dst  = (const int*)d_in[2];
    const int*   et   = (const int*)d_in[3];
    const float* norm = (const float*)d_in[4];
    const float* w1   = (const float*)d_in[5];
    const float* lw1  = (const float*)d_in[6];
    const float* b1   = (const float*)d_in[7];
    const float* w2   = (const float*)d_in[8];
    const float* lw2  = (const float*)d_in[9];
    const float* b2   = (const float*)d_in[10];

    const int M = in_sizes[0] / HDIM;   // 20000
    const int E = in_sizes[1];          // 320000

    float* out = (float*)d_out;
    char*  ws  = (char*)d_ws;

    // ws layout (~13.3 MB)
    size_t off = 0;
    unsigned short* xb  = (unsigned short*)(ws + off); off += (size_t)M * HDIM * 2;
    unsigned short* w1t = (unsigned short*)(ws + off); off += 65536 * 2;
    unsigned short* w2t = (unsigned short*)(ws + off); off += 65536 * 2;
    int* start = (int*)(ws + off);  off += (size_t)(M + 1) * 4; off = (off + 15) & ~15ull;
    int* cnt   = (int*)(ws + off);  off += (size_t)M * 4;       off = (off + 15) & ~15ull;
    int* deg   = (int*)(ws + off);  off += (size_t)M * 4;       off = (off + 15) & ~15ull;
    int2* epack = (int2*)(ws + off); off += (size_t)E * 8;
    (void)ws_size;

    // ---- preprocess: dst-sorted CSR + bf16 conversions ----
    hipMemsetAsync(deg, 0, (size_t)M * 4, stream);
    convert_kernel<<<2048, 256, 0, stream>>>(x, xb, lw1, w1t, lw2, w2t, M * HDIM);
    hist_kernel<<<512, 256, 0, stream>>>(dst, deg, E);
    scan_kernel<<<1, 1024, 0, stream>>>(deg, start, cnt, M);
    scatter_kernel<<<512, 256, 0, stream>>>(src, dst, et, norm, cnt, epack, E);

    const int nblk = (M + WPB - 1) / WPB;
    const int gblk = (M + 31) / 32;

    // Layer 1: agg1 -> out (scratch), xb <- bf16(relu(agg1 + b1 + xb@lw1)) in place
    agg_kernel<<<nblk, 512, 0, stream>>>(xb, epack, start, w1, out, M);
    mfma_gemm<1><<<gblk, 256, 0, stream>>>(xb, w1t, b1, out, nullptr, xb, M);

    // Layer 2: agg2 -> out, out = agg2 + b2 + h@lw2 (element-wise in-place)
    agg_kernel<<<nblk, 512, 0, stream>>>(xb, epack, start, w2, out, M);
    mfma_gemm<0><<<gblk, 256, 0, stream>>>(xb, w2t, b2, out, out, nullptr, M);
}